// Round 7
// baseline (102.822 us; speedup 1.0000x reference)
//
#include <hip/hip_runtime.h>
#include <float.h>

#define NSEG 8
#define SEGLEN 1024   // B*Ls*H*D = 1*4*8*32
#define BIGV 1e30f    // "infinity" for invalid DP cells
#define PADV 1e18f    // x-pad sentinel (huge cost, no overflow)

#define CH 64         // diagonals per chunk (one flag handshake per chunk)
#define NCH 20        // chunks per wave: local diags 0..1279
#define BSTRIDE 1536  // boundary rows -256..1279 -> index row+256 in [0,1536)

#define DPPF(OLD, SRC, CTRL, RM, BM, BC)                                      \
    __int_as_float(__builtin_amdgcn_update_dpp(                               \
        __float_as_int(OLD), __float_as_int(SRC), CTRL, RM, BM, BC))
// lane i <- lane i-1; lane 0 <- OLD[lane 0]   (validated since R2)
#define WSHIFT1(OLD, SRC) DPPF(OLD, SRC, 0x138, 0xF, 0xF, false)
// stream advance: lane i <- lane i+1; lane 63 keeps its (stale) value
#define WSTREAM(SRC) DPPF(SRC, SRC, 0x130, 0xF, 0xF, false)

// One 256-thread block (4 waves) per (qi,kj) pair. Wave w owns columns
// [256w, 256w+256); lane L owns j = 256w + 4L + e, e in [0,4).
// D[i,j] = |x[i]-y[j]| + min3(up, left, diag), along anti-diagonals.
// Cross-wave boundaries flow through bnd[w+1][row+256] (LDS) with per-wave
// monotonic chunk-counter handshakes (no __syncthreads in the main loop).
// R7: all per-step cross-lane traffic is DPP-only. Three per-chunk "stream"
// registers (xsrc / bs / bd) hold the 64 inject values with the value for
// step s at lane s; each step uses lane 0 as the DPP old-operand and the
// stream shifts down one lane (wave_shl1). No v_readlane -> no
// VALU->SGPR->VALU hazard wait-states in the 1280-step hot path.
__global__ __launch_bounds__(256) void dtw4_kernel(const float* __restrict__ q,
                                                   const float* __restrict__ kk,
                                                   float* __restrict__ dists) {
    __shared__ float xl[1280];
    __shared__ float bnd[5][BSTRIDE];  // bnd[0] = BIGV region for wave 0
    __shared__ float dump[128];        // write sink for lanes != 63
    __shared__ int flagsA[5];          // [0]=sentinel; [w+1]=chunks done by wave w
    const int tid = threadIdx.x;
    const int lane = tid & 63;
    const int wv = tid >> 6;
    const int pair = blockIdx.x;       // 0..63
    const float* __restrict__ x = q + (pair >> 3) * SEGLEN;
    const float* __restrict__ y = kk + (pair & 7) * SEGLEN;

    for (int t = tid; t < 1280; t += 256) xl[t] = (t < SEGLEN) ? x[t] : PADV;
    // bnd[0][255] is the virtual corner D[-1,-1] = 0 (row -1 seed for wave 0,
    // chunk 0); every other boundary cell starts as BIGV.
    for (int t = tid; t < 5 * BSTRIDE; t += 256)
        (&bnd[0][0])[t] = (t == 255) ? 0.f : BIGV;
    if (tid < 5) flagsA[tid] = (tid == 0) ? 0x7FFFFFFF : 0;

    float yv[4];
    {
        const float4 y4 = *(const float4*)(y + wv * 256 + lane * 4);
        yv[0] = y4.x; yv[1] = y4.y; yv[2] = y4.z; yv[3] = y4.w;
    }

    float A[4], B[4], xs[4];
#pragma unroll
    for (int e = 0; e < 4; ++e) { A[e] = BIGV; B[e] = BIGV; xs[e] = PADV; }

    __syncthreads();   // the only block-wide barrier

    const float* __restrict__ br = &bnd[wv][0];   // left neighbor's boundary

// One diagonal step (s compile-time). P1 = diag d-1, P2 = diag d-2 & output.
// Descending e so P2[e-1] (diag neighbor) is read before being overwritten.
#define STEP(s, P1, P2)  {                                                    \
    xs[(s) & 3] = WSHIFT1(xsrc, xs[(s) & 3]);                                 \
    const float p1m = WSHIFT1(bs, P1[3]);                                     \
    const float p2m = WSHIFT1(bd, P2[3]);                                     \
    xsrc = WSTREAM(xsrc);                                                     \
    bs = WSTREAM(bs);                                                         \
    bd = WSTREAM(bd);                                                         \
    _Pragma("unroll")                                                         \
    for (int e = 3; e >= 0; --e) {                                            \
        const float up = P1[e];                                               \
        const float lf = (e == 0) ? p1m : P1[e - 1];                          \
        const float dg = (e == 0) ? p2m : P2[e - 1];                          \
        P2[e] = fabsf(xs[((s) - e) & 3] - yv[e]) + fminf(fminf(up, lf), dg);  \
    }                                                                         \
    va[(s)] = P2[3];                                                          \
}
#define STEP2(s) STEP(s, A, B) STEP((s) + 1, B, A)

#pragma unroll 1
    for (int t = 0; t < NCH; ++t) {
        // wait until left neighbor covers boundary rows up to 64t+63 (chunk
        // t+4 done), capped at NCH: indices past its last write are pad rows
        // holding their BIGV initialization.
        const int need = (t + 5 < NCH) ? (t + 5) : NCH;
        while (__hip_atomic_load(&flagsA[wv], __ATOMIC_ACQUIRE,
                                 __HIP_MEMORY_SCOPE_WORKGROUP) < need)
            __builtin_amdgcn_s_sleep(1);

        // stream registers: value for step s sits at lane s
        float xsrc = xl[CH * t + lane];          // x[64t+s]
        float bs = br[CH * t + 256 + lane];      // left boundary row 64t+s
        float bd = br[CH * t + 255 + lane];      // left boundary row 64t+s-1
        // boundary write target: lane 63 -> bnd[wv+1][64t+1+s]; others -> dump
        float* va = (lane == 63) ? &bnd[wv + 1][CH * t + 1] : &dump[lane];

        STEP2(0)  STEP2(2)  STEP2(4)  STEP2(6)  STEP2(8)  STEP2(10)
        STEP2(12) STEP2(14) STEP2(16) STEP2(18) STEP2(20) STEP2(22)
        STEP2(24) STEP2(26) STEP2(28) STEP2(30) STEP2(32) STEP2(34)
        STEP2(36) STEP2(38) STEP2(40) STEP2(42) STEP2(44) STEP2(46)
        STEP2(48) STEP2(50) STEP2(52) STEP2(54) STEP2(56) STEP2(58)
        STEP2(60) STEP2(62)

        // publish chunk t (release orders the ds_writes above before the flag)
        __hip_atomic_store(&flagsA[wv + 1], t + 1, __ATOMIC_RELEASE,
                           __HIP_MEMORY_SCOPE_WORKGROUP);
    }
#undef STEP
#undef STEP2

    // global cell (1023,1023): wave 3, local diag 1278 (chunk 19, s=62 -> B)
    if (wv == 3 && lane == 63) dists[pair] = B[3];
}

// out[i*1024+p] = sum_j softmax_j(0.5*dists[i,:])[j] * values[j*1024+p]
__global__ __launch_bounds__(256) void softmax_out_kernel(const float* __restrict__ v,
                                                          const float* __restrict__ dists,
                                                          float* __restrict__ out) {
    const int o = blockIdx.x * blockDim.x + threadIdx.x;
    if (o >= NSEG * SEGLEN) return;
    const int i = o >> 10;
    const int p = o & 1023;

    float l[NSEG];
    float mx = -FLT_MAX;
#pragma unroll
    for (int j = 0; j < NSEG; ++j) {
        l[j] = 0.5f * dists[i * NSEG + j];
        mx = fmaxf(mx, l[j]);
    }
    float s = 0.f;
#pragma unroll
    for (int j = 0; j < NSEG; ++j) {
        l[j] = expf(l[j] - mx);
        s += l[j];
    }
    const float inv = 1.f / s;
    float acc = 0.f;
#pragma unroll
    for (int j = 0; j < NSEG; ++j) acc += (l[j] * inv) * v[j * SEGLEN + p];
    out[o] = acc;
}

extern "C" void kernel_launch(void* const* d_in, const int* in_sizes, int n_in,
                              void* d_out, int out_size, void* d_ws, size_t ws_size,
                              hipStream_t stream) {
    const float* q = (const float*)d_in[0];   // queries [1,32,8,32] f32
    const float* k = (const float*)d_in[1];   // keys
    const float* v = (const float*)d_in[2];   // values
    float* out = (float*)d_out;               // [8192] f32
    float* dists = (float*)d_ws;              // 64 floats scratch

    dtw4_kernel<<<dim3(NSEG * NSEG), dim3(256), 0, stream>>>(q, k, dists);
    softmax_out_kernel<<<dim3((NSEG * SEGLEN + 255) / 256), dim3(256), 0, stream>>>(v, dists, out);
}

// Round 9
// 86.974 us; speedup vs baseline: 1.1822x; 1.1822x over previous
//
#include <hip/hip_runtime.h>
#include <float.h>

#define NSEG 8
#define SEGLEN 1024   // B*Ls*H*D = 1*4*8*32
#define BIGV 1e30f    // "infinity" for invalid DP cells
#define PADV 1e18f    // x-pad sentinel (huge cost, no overflow)

#define NW 8          // waves per block (512 threads); wave owns 128 cols
#define CH 64         // diagonals per chunk (one flag handshake per chunk)
#define NCH 18        // chunks per wave: local diags 0..1151 (1024+127 real)
#define LAGCH 3       // consumer chunk t needs producer flag >= t+3
#define BOFF 128      // boundary row offset (row r -> index r+BOFF)
#define BSTRIDE 1280  // rows -128..1151

#define DPPF(OLD, SRC, CTRL, RM, BM, BC)                                      \
    __int_as_float(__builtin_amdgcn_update_dpp(                               \
        __float_as_int(OLD), __float_as_int(SRC), CTRL, RM, BM, BC))
// lane i <- lane i-1; lane 0 <- OLD[lane 0]   (validated R2-R6)
#define WSHIFT1(OLD, SRC) DPPF(OLD, SRC, 0x138, 0xF, 0xF, false)

__device__ __forceinline__ float readlaneF(float v, int l) {
    return __int_as_float(__builtin_amdgcn_readlane(__float_as_int(v), l));
}

// One 512-thread block (8 waves) per (qi,kj) pair. Wave w owns columns
// [128w, 128w+128); lane L owns j = 128w + 2L + e, e in {0,1}.
// D[i,j] = |x[i]-y[j]| + min3(up, left, diag), along anti-diagonals.
// Cross-wave boundary values flow through bnd[w+1][row+BOFF] in LDS; sync is
// a per-wave monotonic chunk counter (release store / acquire spin).
// R8 bug (fixed here): dump[] sink must hold lane+s <= 125 entries -- the
// hot loop writes va[s] = &dump[lane] + s for lanes 0..62, s 0..63. dump[64]
// overflowed into flagsA/bnd (LDS corruption -> absmax 2.78). dump[128] is
// the R6-proven safe size.
__global__ __launch_bounds__(512) void dtw8_kernel(const float* __restrict__ q,
                                                   const float* __restrict__ kk,
                                                   float* __restrict__ dists) {
    __shared__ float xl[1280];
    __shared__ float bnd[NW + 1][BSTRIDE];  // bnd[0] = BIGV region for wave 0
    __shared__ float dump[128];             // write sink, indices up to 125
    __shared__ int flagsA[NW + 1];          // [0]=sentinel; [w+1]=wave w chunks done
    const int tid = threadIdx.x;
    const int lane = tid & 63;
    const int wv = tid >> 6;
    const int pair = blockIdx.x;            // 0..63
    const float* __restrict__ x = q + (pair >> 3) * SEGLEN;
    const float* __restrict__ y = kk + (pair & 7) * SEGLEN;

    for (int t = tid; t < 1280; t += 512) xl[t] = (t < SEGLEN) ? x[t] : PADV;
    // bnd[0][BOFF-1] = 127 is the virtual corner D[-1,-1] = 0 (diag seed for
    // wave 0 chunk 0); everything else starts BIGV.
    for (int t = tid; t < (NW + 1) * BSTRIDE; t += 512)
        (&bnd[0][0])[t] = (t == BOFF - 1) ? 0.f : BIGV;
    if (tid < NW + 1) flagsA[tid] = (tid == 0) ? 0x7FFFFFFF : 0;

    float yv[2];
    {
        const float2 y2 = *(const float2*)(y + wv * 128 + lane * 2);
        yv[0] = y2.x; yv[1] = y2.y;
    }

    float A[2], B[2], xs[2];
    A[0] = A[1] = B[0] = B[1] = BIGV;
    xs[0] = xs[1] = PADV;

    __syncthreads();   // the only block-wide barrier

    const float* __restrict__ br = &bnd[wv][0];   // left neighbor's boundary

// One diagonal step (s compile-time). P1 = diag d-1, P2 = diag d-2 & output.
// e=1 computed first so P2[0] (diag neighbor of e=1) is read before overwrite.
#define STEP(s, P1, P2)  {                                                    \
    const float xinj = readlaneF(xv, (s));                                    \
    xs[(s) & 1] = WSHIFT1(xinj, xs[(s) & 1]);                                 \
    const float linj = ((s) == CH - 1) ? bvx : readlaneF(bvv, (s) + 1);       \
    const float p1m = WSHIFT1(linj, P1[1]);                                   \
    const float p2m = WSHIFT1(dinj, P2[1]);                                   \
    {                                                                         \
        const float u1 = P1[1], l1 = P1[0], g1 = P2[0];                       \
        P2[1] = fabsf(xs[((s) + 1) & 1] - yv[1]) + fminf(fminf(u1, l1), g1);  \
        const float u0 = P1[0];                                               \
        P2[0] = fabsf(xs[(s) & 1] - yv[0]) + fminf(fminf(u0, p1m), p2m);      \
    }                                                                         \
    va[(s)] = P2[1];                                                          \
    dinj = linj;                                                              \
}
#define STEP2(s) STEP(s, A, B) STEP((s) + 1, B, A)

#pragma unroll 1
    for (int t = 0; t < NCH; ++t) {
        // wait until left neighbor covers boundary rows up to 64t+63 (its
        // local diag 64t+190 -> chunk t+2 done -> flag >= t+3), capped at
        // NCH: later rows are pad rows holding their BIGV initialization.
        const int need = (t + LAGCH < NCH) ? (t + LAGCH) : NCH;
        while (__hip_atomic_load(&flagsA[wv], __ATOMIC_ACQUIRE,
                                 __HIP_MEMORY_SCOPE_WORKGROUP) < need)
            __builtin_amdgcn_s_sleep(1);

        const float xv = xl[CH * t + lane];             // x[64t+s] inject stream
        const float bvv = br[CH * t + BOFF - 1 + lane]; // rows 64t-1..64t+62
        const float bvx = br[CH * t + BOFF + 63];       // row 64t+63 (uniform)
        float dinj = readlaneF(bvv, 0);                 // row 64t-1 diag seed
        // boundary write: lane 63 -> bnd[wv+1][64t+1+s]; others -> dump
        float* va = (lane == 63) ? &bnd[wv + 1][CH * t + 1] : &dump[lane];

        STEP2(0)  STEP2(2)  STEP2(4)  STEP2(6)  STEP2(8)  STEP2(10)
        STEP2(12) STEP2(14) STEP2(16) STEP2(18) STEP2(20) STEP2(22)
        STEP2(24) STEP2(26) STEP2(28) STEP2(30) STEP2(32) STEP2(34)
        STEP2(36) STEP2(38) STEP2(40) STEP2(42) STEP2(44) STEP2(46)
        STEP2(48) STEP2(50) STEP2(52) STEP2(54) STEP2(56) STEP2(58)
        STEP2(60) STEP2(62)

        // publish chunk t (release orders the ds_writes above before the flag)
        __hip_atomic_store(&flagsA[wv + 1], t + 1, __ATOMIC_RELEASE,
                           __HIP_MEMORY_SCOPE_WORKGROUP);
    }
#undef STEP
#undef STEP2

    // global cell (1023,1023): wave 7, local diag 1150 (chunk 17, s=62 -> B),
    // col 127local = lane 63, e=1.
    if (wv == NW - 1 && lane == 63) dists[pair] = B[1];
}

// out[i*1024+p] = sum_j softmax_j(0.5*dists[i,:])[j] * values[j*1024+p]
__global__ __launch_bounds__(256) void softmax_out_kernel(const float* __restrict__ v,
                                                          const float* __restrict__ dists,
                                                          float* __restrict__ out) {
    const int o = blockIdx.x * blockDim.x + threadIdx.x;
    if (o >= NSEG * SEGLEN) return;
    const int i = o >> 10;
    const int p = o & 1023;

    float l[NSEG];
    float mx = -FLT_MAX;
#pragma unroll
    for (int j = 0; j < NSEG; ++j) {
        l[j] = 0.5f * dists[i * NSEG + j];
        mx = fmaxf(mx, l[j]);
    }
    float s = 0.f;
#pragma unroll
    for (int j = 0; j < NSEG; ++j) {
        l[j] = expf(l[j] - mx);
        s += l[j];
    }
    const float inv = 1.f / s;
    float acc = 0.f;
#pragma unroll
    for (int j = 0; j < NSEG; ++j) acc += (l[j] * inv) * v[j * SEGLEN + p];
    out[o] = acc;
}

extern "C" void kernel_launch(void* const* d_in, const int* in_sizes, int n_in,
                              void* d_out, int out_size, void* d_ws, size_t ws_size,
                              hipStream_t stream) {
    const float* q = (const float*)d_in[0];   // queries [1,32,8,32] f32
    const float* k = (const float*)d_in[1];   // keys
    const float* v = (const float*)d_in[2];   // values
    float* out = (float*)d_out;               // [8192] f32
    float* dists = (float*)d_ws;              // 64 floats scratch

    dtw8_kernel<<<dim3(NSEG * NSEG), dim3(512), 0, stream>>>(q, k, dists);
    softmax_out_kernel<<<dim3((NSEG * SEGLEN + 255) / 256), dim3(256), 0, stream>>>(v, dists, out);
}

// Round 10
// 78.582 us; speedup vs baseline: 1.3085x; 1.1068x over previous
//
#include <hip/hip_runtime.h>
#include <float.h>

#define NSEG 8
#define SEGLEN 1024   // B*Ls*H*D = 1*4*8*32
#define BIGV 1e30f    // "infinity" for invalid DP cells
#define PADV 1e18f    // x-pad sentinel: huge cost, no overflow over 64+ steps

#define NW 8          // waves per block (512 threads); wave owns 128 cols
#define CH 64         // steps per chunk (one flag handshake per chunk)
#define NCH 17        // local steps 0..1087 (row r = t - lane, r valid 0..1023)
#define XLEN 1152     // x staged with PADV pad (indices 1024..1151)
#define BSTRIDE 1160  // bnd[w][r+64] = D[r, 128w-1]; max read index 1152

#define DPPF(OLD, SRC, CTRL, RM, BM, BC)                                      \
    __int_as_float(__builtin_amdgcn_update_dpp(                               \
        __float_as_int(OLD), __float_as_int(SRC), CTRL, RM, BM, BC))
// lane i <- lane i-1; lane 0 <- OLD[lane 0]   (validated R2-R9)
#define WSHIFT1(OLD, SRC) DPPF(OLD, SRC, 0x138, 0xF, 0xF, false)

__device__ __forceinline__ float readlaneF(float v, int l) {
    return __int_as_float(__builtin_amdgcn_readlane(__float_as_int(v), l));
}

// Lane-skewed systolic DTW. One 512-thread block (8 waves) per (qi,kj) pair.
// Wave w owns cols [128w,128w+128); lane L owns c0=128w+2L, c1=c0+1.
// At local step t, lane L computes ROW r = t - L of its two columns:
//   cell0: D[r,c0] = |x[r]-y0| + min3(P0(up), lf(left), dgl(diag))
//   cell1: D[r,c1] = |x[r]-y1| + min3(P1(up), cell0(left), P0(diag))
// Lane L-1 runs one row AHEAD of lane L, so its c1 outputs for rows r, r-1
// were computed at steps t-1, t-2: ONE end-of-step DPP shift (n1) delivers
// next step's lf; dgl is last step's lf. No same-step cross-lane dependency
// -> the per-step critical path is within-lane only (~5 VALU ops).
// x streams systolically: xreg = shift(xreg) with x[t] injected at lane 0.
// Rows r<0 / r>1023 compute garbage that stays >= 1e18 (PADV costs) and is
// never selected by any min over real values (<= ~1e4).
// Cross-wave boundary: lane 63 writes D[r,128w+127] to bnd[w+1][r+64] every
// step (others write to a dump sink -- branchless); monotone chunk-counter
// handshake, LAGCH=2 (consumer chunk tc reads bnd indices <= 64*tc+128).
__global__ __launch_bounds__(512) void dtw_sk_kernel(const float* __restrict__ q,
                                                     const float* __restrict__ kk,
                                                     float* __restrict__ dists) {
    __shared__ float xl[XLEN];
    __shared__ float bnd[NW + 1][BSTRIDE];  // bnd[0] = BIGV region for wave 0
    __shared__ float dump[128];             // sink, indices up to 125 (R8 lesson)
    __shared__ int flagsA[NW + 1];          // [0]=sentinel; [w+1]=wave w chunks done
    const int tid = threadIdx.x;
    const int lane = tid & 63;
    const int wv = tid >> 6;
    const int pair = blockIdx.x;            // 0..63
    const float* __restrict__ x = q + (pair >> 3) * SEGLEN;
    const float* __restrict__ y = kk + (pair & 7) * SEGLEN;

    for (int t = tid; t < XLEN; t += 512) xl[t] = (t < SEGLEN) ? x[t] : PADV;
    // flat index 63 = bnd[0][63] = virtual corner D[-1,-1] = 0; rest BIGV.
    for (int t = tid; t < (NW + 1) * BSTRIDE; t += 512)
        (&bnd[0][0])[t] = (t == 63) ? 0.f : BIGV;
    if (tid < NW + 1) flagsA[tid] = (tid == 0) ? 0x7FFFFFFF : 0;

    const float2 y2 = *(const float2*)(y + wv * 128 + lane * 2);
    const float yv0 = y2.x, yv1 = y2.y;

    __syncthreads();   // the only block-wide barrier

    const float* __restrict__ br = &bnd[wv][0];   // left neighbor's boundary

    // wait for the first 2 producer chunks, then read init boundary values
    {
        const int need0 = (NCH < 2) ? NCH : 2;
        while (__hip_atomic_load(&flagsA[wv], __ATOMIC_ACQUIRE,
                                 __HIP_MEMORY_SCOPE_WORKGROUP) < need0)
            __builtin_amdgcn_s_sleep(1);
    }
    float P0 = BIGV, P1 = BIGV, xreg = PADV;
    float lf = br[64];    // D[0, 128w-1] (wave 0: BIGV)
    float dgl = br[63];   // D[-1,128w-1] (wave 0: corner 0)

// One systolic step (s compile-time within chunk). Order matters: cells use
// the OLD lf/dgl, then the n1 shift prepares next step's lf.
#define STEP(s) {                                                             \
    xreg = WSHIFT1(readlaneF(xv, (s)), xreg);                                 \
    const float c0n = fabsf(xreg - yv0) + fminf(fminf(P0, lf), dgl);          \
    const float c1n = fabsf(xreg - yv1) + fminf(fminf(P1, c0n), P0);          \
    const float n1 = WSHIFT1(readlaneF(bvv, (s)), c1n);                       \
    dgl = lf; lf = n1; P0 = c0n; P1 = c1n;                                    \
    va[(s)] = c1n;                                                            \
}
#define STEP8(s) STEP(s) STEP((s)+1) STEP((s)+2) STEP((s)+3)                  \
                 STEP((s)+4) STEP((s)+5) STEP((s)+6) STEP((s)+7)

#pragma unroll 1
    for (int tc = 0; tc < NCH; ++tc) {
        // consumer chunk tc reads bnd indices up to 64*tc+128 -> producer
        // must have finished chunk tc+1 (flag >= tc+2), capped at NCH
        // (later indices are unwritten BIGV pad).
        const int need = (tc + 2 < NCH) ? (tc + 2) : NCH;
        while (__hip_atomic_load(&flagsA[wv], __ATOMIC_ACQUIRE,
                                 __HIP_MEMORY_SCOPE_WORKGROUP) < need)
            __builtin_amdgcn_s_sleep(1);

        const float xv = xl[CH * tc + lane];         // x[64tc+s] inject stream
        const float bvv = br[CH * tc + 65 + lane];   // binj(s): bnd row 64tc+s+1
        // boundary write: lane 63 -> bnd[wv+1][64tc+1+s] (= row r+64); others -> dump
        float* va = (lane == 63) ? &bnd[wv + 1][CH * tc + 1] : &dump[lane];

        STEP8(0) STEP8(8) STEP8(16) STEP8(24) STEP8(32) STEP8(40) STEP8(48) STEP8(56)

        // publish chunk tc (release orders the ds_writes above before the flag)
        __hip_atomic_store(&flagsA[wv + 1], tc + 1, __ATOMIC_RELEASE,
                           __HIP_MEMORY_SCOPE_WORKGROUP);
    }
#undef STEP
#undef STEP8

    // D[1023,1023] was written by wave 7 lane 63 at t=1086 to bnd[8][1087]
    // (t=1087 overwrites P1 with a garbage row, so read it back from LDS).
    if (wv == NW - 1 && lane == 0) dists[pair] = bnd[NW][1087];
}

// out[i*1024+p] = sum_j softmax_j(0.5*dists[i,:])[j] * values[j*1024+p]
__global__ __launch_bounds__(256) void softmax_out_kernel(const float* __restrict__ v,
                                                          const float* __restrict__ dists,
                                                          float* __restrict__ out) {
    const int o = blockIdx.x * blockDim.x + threadIdx.x;
    if (o >= NSEG * SEGLEN) return;
    const int i = o >> 10;
    const int p = o & 1023;

    float l[NSEG];
    float mx = -FLT_MAX;
#pragma unroll
    for (int j = 0; j < NSEG; ++j) {
        l[j] = 0.5f * dists[i * NSEG + j];
        mx = fmaxf(mx, l[j]);
    }
    float s = 0.f;
#pragma unroll
    for (int j = 0; j < NSEG; ++j) {
        l[j] = expf(l[j] - mx);
        s += l[j];
    }
    const float inv = 1.f / s;
    float acc = 0.f;
#pragma unroll
    for (int j = 0; j < NSEG; ++j) acc += (l[j] * inv) * v[j * SEGLEN + p];
    out[o] = acc;
}

extern "C" void kernel_launch(void* const* d_in, const int* in_sizes, int n_in,
                              void* d_out, int out_size, void* d_ws, size_t ws_size,
                              hipStream_t stream) {
    const float* q = (const float*)d_in[0];   // queries [1,32,8,32] f32
    const float* k = (const float*)d_in[1];   // keys
    const float* v = (const float*)d_in[2];   // values
    float* out = (float*)d_out;               // [8192] f32
    float* dists = (float*)d_ws;              // 64 floats scratch

    dtw_sk_kernel<<<dim3(NSEG * NSEG), dim3(512), 0, stream>>>(q, k, dists);
    softmax_out_kernel<<<dim3((NSEG * SEGLEN + 255) / 256), dim3(256), 0, stream>>>(v, dists, out);
}